// Round 1
// baseline (129.232 us; speedup 1.0000x reference)
//
#include <hip/hip_runtime.h>

// out[128,16384] = [A|B](128x8384) @ [x; x2](8384x16384), bf16 MFMA.
// Round 10 = round 9 + occupancy + dispatch fusion:
//   - split-K x4 (grid 128x4 = 512 blocks = 2 blocks/CU, 16 waves/CU):
//     round 9 was latency-bound at 1 block/CU (MfmaUtil 21%, VALUBusy 34%,
//     HBM 5.6%, Occupancy 17% -> ~75% dependency stall). LDS 37.4KB and
//     VGPR 60 both allow 2+ blocks/CU; grid was the only limiter.
//   - build fused to ONE dispatch (build_all): closed-form pair math
//     (cumN/offR invertible by 7-step branchless binary search) removes the
//     pp-table dependency, so {out zeroing + pp build + wt build} run in a
//     single dependency-free kernel. 4 dispatches -> 2, hipMemsetAsync gone.
//     wt written as b128 (8 elem/thread), B read as 32B runs.
// DO NOT add __launch_bounds__ min-waves: (256,8) clamped VGPR -> spills (r6).
// K permutation: identity k'<128 (steps 0-1) | NICE [128,7936) (steps 2-123,
// uniform i, aligned j-octet) | RAGGED [7936,8384) (steps 124-130, gather).

constexpr int N_     = 128;
constexpr int S_     = 8256;
constexpr int BATCH_ = 16384;
constexpr int KTOT   = 8384;         // 131*64
constexpr int NKT    = 131;
constexpr int LD     = 136;          // xt row stride (ushorts); rows 272B = 17x16B
constexpr size_t WT_BYTES = (size_t)KTOT * 128 * 2;
constexpr size_t PP_OFF   = WT_BYTES;

typedef __attribute__((ext_vector_type(8))) short short8;
typedef __attribute__((ext_vector_type(4))) float f32x4;
typedef __attribute__((ext_vector_type(2))) float f32x2;

__device__ __forceinline__ float bf2f(ushort h) {
    unsigned u = (unsigned)h << 16;
    float f;
    __builtin_memcpy(&f, &u, 4);
    return f;
}
__device__ __forceinline__ ushort f2bf(float f) {   // RNE (staging/build only)
    unsigned u;
    __builtin_memcpy(&u, &f, 4);
    u = (u + 0x7FFFu + ((u >> 16) & 1u)) >> 16;
    return (ushort)u;
}
__device__ __forceinline__ uint fbits(float f) {
    uint u; __builtin_memcpy(&u, &f, 4); return u;
}

// ---------- closed-form permutation helpers ----------
// cumN(i) = #NICE octets for rows < i = sum_{q<i} (16 - ceil(q/8))
__device__ __forceinline__ int cumN(int i) {
    if (i <= 0) return 0;
    const int n = i - 1, t = n >> 3, r = n & 7;
    return 16 * i - (4 * t * (t + 1) + r * (t + 1));
}
// offR(i) = #ragged entries for rows < i = sum_{q<i} ((8-(q&7))&7)
__device__ __forceinline__ int offR(int i) {
    const int a = i >> 3, b = i & 7;
    const int p = b ? (8 * (b - 1) - (((b - 1) * b) >> 1)) : 0;
    return 28 * a + p;
}
__device__ __forceinline__ int triS(int i) { return i * (257 - i) / 2; }

// ---------- fused build: zero out + pp table + wt (no internal deps) ----------
// W section (blocks [0,524)): thread (ko,m) -> 8 wt elems (one b128 store).
//   wt elem e = kt*8192 + kk*4096 + wm*2048 + mt*512 + lane*8 + el holds
//   W[m = wm*64+mt*16+(lane&15)][ perm(kt*64 + kk*32 + (lane>>4)*8 + el) ]
// Z section (blocks [524,780)): zero out[128,16384].
// P section (block 780): pp[k'] = i | (j<<8)  (j=0xFF marks A column i).
__global__ __launch_bounds__(256) void build_all(
    const float* __restrict__ A, const float* __restrict__ B,
    ushort* __restrict__ pp, ushort* __restrict__ wt,
    float* __restrict__ out)
{
    const int bid = blockIdx.x, t = threadIdx.x;
    if (bid < 524) {                              // ---- W: 1048 k-octets x 128 m ----
        const int idx = bid * 256 + t;            // [0, 134144)
        const int ko  = idx >> 7;                 // k-octet
        const int m   = idx & 127;
        const int kt = ko >> 3, kk = (ko >> 2) & 1, oct = ko & 3;
        const int lane = oct * 16 + (m & 15);
        const int e0 = kt * 8192 + kk * 4096 + (m >> 6) * 2048 +
                       ((m >> 4) & 3) * 512 + lane * 8;
        float v[8];
        if (ko < 16) {                            // identity: k = ko*8+el, A[m][k]
            const int i0 = ko * 8;
            #pragma unroll
            for (int el = 0; el < 8; ++el) v[el] = A[m * 128 + i0 + el];
        } else if (ko < 992) {                    // NICE: uniform i, aligned j-octet
            const int o = ko - 16;
            int i = 0;
            #pragma unroll
            for (int st = 64; st >= 1; st >>= 1) {
                const int c = i + st;
                if (c < 128 && cumN(c) <= o) i = c;
            }
            const int jb = ((i + 7) >> 3) + (o - cumN(i));
            const int s0 = triS(i) + jb * 8 - i;  // s = tri(i) + (j - i)
            const float* bp = B + (size_t)m * S_ + s0;
            #pragma unroll
            for (int el = 0; el < 8; ++el) v[el] = bp[el];
        } else {                                  // RAGGED: per-el gather
            const int kb = ko * 8 - 7936;
            #pragma unroll
            for (int el = 0; el < 8; ++el) {
                const int kloc = kb + el;
                int i = 0;
                #pragma unroll
                for (int st = 64; st >= 1; st >>= 1) {
                    const int c = i + st;
                    if (c < 128 && offR(c) <= kloc) i = c;
                }
                v[el] = B[(size_t)m * S_ + triS(i) + (kloc - offR(i))];
            }
        }
        ushort o8[8];
        #pragma unroll
        for (int el = 0; el < 8; ++el) o8[el] = f2bf(v[el]);
        __builtin_memcpy(wt + e0, o8, 16);
    } else if (bid < 780) {                       // ---- Z: zero out ----
        const int zb = bid - 524;
        f32x4* o4 = (f32x4*)out;
        #pragma unroll
        for (int c = 0; c < 4; ++c)
            o4[(size_t)zb * 2048 + c * 512 + t] = (f32x4){0.f, 0.f, 0.f, 0.f};
    } else {                                      // ---- P: pp table ----
        const int i = t;
        if (i < 128) {
            pp[i] = (ushort)(i | (0xFFu << 8));
            const int jb0 = (i + 7) >> 3;
            int kb = 128 + cumN(i) * 8;
            for (int jb = jb0; jb < 16; ++jb) {
                #pragma unroll
                for (int e = 0; e < 8; ++e)
                    pp[kb + e] = (ushort)(i | ((jb * 8 + e) << 8));
                kb += 8;
            }
            const int h = (8 - (i & 7)) & 7;
            const int rb = 7936 + offR(i);
            for (int e = 0; e < h; ++e)
                pp[rb + e] = (ushort)(i | ((i + e) << 8));
        }
    }
}

// A-frags for step kt: 8 lane-linear b128 loads (coalesced layout).
__device__ __forceinline__ void load_af(short8 af[8], const ushort* __restrict__ wt,
                                        int kt, int wm, int lane) {
    const ushort* ab = wt + ((size_t)kt << 13) + (wm << 11) + (lane << 3);
    #pragma unroll
    for (int kk = 0; kk < 2; ++kk)
        #pragma unroll
        for (int mt = 0; mt < 4; ++mt)
            af[kk * 4 + mt] = *(const short8*)(ab + (kk << 12) + (mt << 9));
}

// NICE-step: gen B-frags from compact pair word + MFMA.
__device__ __forceinline__ void step_nice(f32x4 acc[4][2], const short8 af[8],
                                          uint prc, const ushort* __restrict__ xr0,
                                          const ushort* __restrict__ xr1) {
    const uint i0a = prc & 0xFFu, j0a = (prc >> 8) & 0xFFu;
    const uint i0b = (prc >> 16) & 0xFFu, j0b = prc >> 24;
    // all 8 LDS reads independent -> one lgkm window
    const ushort xia0 = xr0[i0a], xia1 = xr1[i0a];
    const ushort xib0 = xr0[i0b], xib1 = xr1[i0b];
    uint wa0[4], wa1[4], wb0[4], wb1[4];
    __builtin_memcpy(wa0, xr0 + j0a, 16);
    __builtin_memcpy(wa1, xr1 + j0a, 16);
    __builtin_memcpy(wb0, xr0 + j0b, 16);
    __builtin_memcpy(wb1, xr1 + j0b, 16);

    short8 bfr[2][2];
    #pragma unroll
    for (int v = 0; v < 4; ++v) {
        const uint*  wsx = (v == 0) ? wa0 : (v == 1) ? wa1 : (v == 2) ? wb0 : wb1;
        const ushort xis = (v == 0) ? xia0 : (v == 1) ? xia1 : (v == 2) ? xib0 : xib1;
        const float xi = bf2f(xis);
        const f32x2 xi2 = {xi, xi};
        uint ow[4];
        #pragma unroll
        for (int p = 0; p < 4; ++p) {
            const uint lo = wsx[p] << 16;
            const uint hi = wsx[p] & 0xFFFF0000u;
            f32x2 a;
            { float fl, fh;
              __builtin_memcpy(&fl, &lo, 4);
              __builtin_memcpy(&fh, &hi, 4);
              a.x = fl; a.y = fh; }
            const f32x2 o = a * xi2;                      // v_pk_mul_f32
            ow[p] = __builtin_amdgcn_perm(fbits(o.y), fbits(o.x),
                                          0x07060302u);   // hi16|hi16 trunc pack
        }
        __builtin_memcpy(&bfr[v >> 1][v & 1], ow, 16);
    }
    #pragma unroll
    for (int kk = 0; kk < 2; ++kk)
        #pragma unroll
        for (int mt = 0; mt < 4; ++mt)
            #pragma unroll
            for (int nt = 0; nt < 2; ++nt)
                acc[mt][nt] = __builtin_amdgcn_mfma_f32_16x16x32_bf16(
                    af[kk * 4 + mt], bfr[kk][nt], acc[mt][nt], 0, 0, 0);
}

// ---------- phase 2: fused MFMA GEMM, 128x128 tile, split-K x4 ----------
__global__ __launch_bounds__(512) void gemm_mfma(
    const float*  __restrict__ x,
    const ushort* __restrict__ wt,
    const ushort* __restrict__ pp,
    float* __restrict__ out)
{
    __shared__ ushort xt[128 * LD];    // 34.8 KB: xt[n*LD + r] = bf16 x[r][b0+n]
    __shared__ uint   ppc[NKT * 4];    // 2.1 KB: i0a|j0a<<8|i0b<<16|j0b<<24 per (kt,quad)

    const int t    = threadIdx.x;
    const int b0   = blockIdx.x * 128;
    const int sp   = blockIdx.y;       // 0..3
    const int kt0  = sp * 33;          // 0,33,66,99
    const int kt1  = (sp == 3) ? NKT : kt0 + 33;
    const int lane = t & 63;
    const int w    = t >> 6;
    const int wm   = w >> 2, wn = w & 3;
    const int l16  = lane & 15, quad = lane >> 4;

    // ---- stage xt: coalesced global reads, RNE, b128 LDS writes ----
    {
        const int n = t & 127, g = t >> 7;
        #pragma unroll
        for (int c = 0; c < 4; ++c) {
            const int rb = g * 32 + c * 8;
            uint ow[4];
            #pragma unroll
            for (int p = 0; p < 4; ++p) {
                const ushort u0 = f2bf(x[(size_t)(rb + 2 * p) * BATCH_ + b0 + n]);
                const ushort u1 = f2bf(x[(size_t)(rb + 2 * p + 1) * BATCH_ + b0 + n]);
                ow[p] = (uint)u0 | ((uint)u1 << 16);
            }
            __builtin_memcpy(&xt[n * LD + rb], ow, 16);
        }
    }
    // ---- stage ppc ----
    for (int idx = t; idx < NKT * 4; idx += 512) {
        const int kt = idx >> 2, q = idx & 3;
        const uint w0 = *(const uint*)(pp + kt * 64 + q * 8);
        const uint w1 = *(const uint*)(pp + kt * 64 + 32 + q * 8);
        ppc[idx] = (w0 & 0xFFFFu) | ((w1 & 0xFFFFu) << 16);
    }
    __syncthreads();

    f32x4 acc[4][2];
    #pragma unroll
    for (int mt = 0; mt < 4; ++mt)
        #pragma unroll
        for (int nt = 0; nt < 2; ++nt)
            acc[mt][nt] = (f32x4){0.f, 0.f, 0.f, 0.f};

    const ushort* xr0 = xt + (wn * 32 + l16) * LD;
    const ushort* xr1 = xr0 + 16 * LD;

    // ================= identity steps (kt = 0,1; sp==0 only) =================
    if (sp == 0) {
        for (int kt = 0; kt < 2; ++kt) {
            short8 af[8];
            load_af(af, wt, kt, wm, lane);
            short8 bfr[2][2];
            #pragma unroll
            for (int kk = 0; kk < 2; ++kk) {
                const int off = kt * 64 + kk * 32 + quad * 8;
                bfr[kk][0] = *(const short8*)(xr0 + off);
                bfr[kk][1] = *(const short8*)(xr1 + off);
            }
            #pragma unroll
            for (int kk = 0; kk < 2; ++kk)
                #pragma unroll
                for (int mt = 0; mt < 4; ++mt)
                    #pragma unroll
                    for (int nt = 0; nt < 2; ++nt)
                        acc[mt][nt] = __builtin_amdgcn_mfma_f32_16x16x32_bf16(
                            af[kk * 4 + mt], bfr[kk][nt], acc[mt][nt], 0, 0, 0);
        }
    }

    // ================= NICE steps, software-pipelined =================
    {
        const int s_ni = (kt0 > 2) ? kt0 : 2;
        const int e_ni = (kt1 < 124) ? kt1 : 124;
        int kt = s_ni;
        if (kt < e_ni) {
            short8 afA[8], afB[8];
            load_af(afA, wt, kt, wm, lane);
            uint prc = ppc[kt * 4 + quad];
            while (true) {
                {   // consume afA, prefetch afB
                    const int ktn = (kt + 1 < e_ni) ? kt + 1 : kt;
                    load_af(afB, wt, ktn, wm, lane);
                    const uint prn = ppc[ktn * 4 + quad];
                    step_nice(acc, afA, prc, xr0, xr1);
                    prc = prn; ++kt;
                }
                if (kt >= e_ni) break;
                {   // consume afB, prefetch afA
                    const int ktn = (kt + 1 < e_ni) ? kt + 1 : kt;
                    load_af(afA, wt, ktn, wm, lane);
                    const uint prn = ppc[ktn * 4 + quad];
                    step_nice(acc, afB, prc, xr0, xr1);
                    prc = prn; ++kt;
                }
                if (kt >= e_ni) break;
            }
        }
    }

    // ================= ragged steps (kt = 124..130; sp==3 only) =================
    if (sp == 3) {
        for (int kt = 124; kt < NKT; ++kt) {
            short8 af[8];
            load_af(af, wt, kt, wm, lane);
            short8 bfr[2][2];
            #pragma unroll
            for (int kk = 0; kk < 2; ++kk) {
                const int k0 = kt * 64 + kk * 32 + quad * 8;
                const uint4 pk = *(const uint4*)(pp + k0);
                const uint pr4[4] = {pk.x, pk.y, pk.z, pk.w};
                #pragma unroll
                for (int nt = 0; nt < 2; ++nt) {
                    const ushort* xr = nt ? xr1 : xr0;
                    float prods[8];
                    #pragma unroll
                    for (int e = 0; e < 8; ++e) {
                        const uint ent = (pr4[e >> 1] >> ((e & 1) * 16)) & 0xFFFFu;
                        prods[e] = bf2f(xr[ent & 0xFFu]) * bf2f(xr[ent >> 8]);
                    }
                    uint ow[4];
                    #pragma unroll
                    for (int p = 0; p < 4; ++p)
                        ow[p] = __builtin_amdgcn_perm(fbits(prods[2 * p + 1]),
                                                      fbits(prods[2 * p]),
                                                      0x07060302u);
                    __builtin_memcpy(&bfr[kk][nt], ow, 16);
                }
            }
            #pragma unroll
            for (int kk = 0; kk < 2; ++kk)
                #pragma unroll
                for (int mt = 0; mt < 4; ++mt)
                    #pragma unroll
                    for (int nt = 0; nt < 2; ++nt)
                        acc[mt][nt] = __builtin_amdgcn_mfma_f32_16x16x32_bf16(
                            af[kk * 4 + mt], bfr[kk][nt], acc[mt][nt], 0, 0, 0);
        }
    }

    // ---- epilogue: atomic accumulate (C/D: col=lane&15, row=quad*4+reg) ----
    #pragma unroll
    for (int mt = 0; mt < 4; ++mt) {
        #pragma unroll
        for (int nt = 0; nt < 2; ++nt) {
            const int mbase = wm * 64 + mt * 16 + quad * 4;
            const size_t col = (size_t)b0 + wn * 32 + nt * 16 + l16;
            #pragma unroll
            for (int r = 0; r < 4; ++r)
                unsafeAtomicAdd(&out[(size_t)(mbase + r) * BATCH_ + col],
                                acc[mt][nt][r]);
        }
    }
}

extern "C" void kernel_launch(void* const* d_in, const int* in_sizes, int n_in,
                              void* d_out, int out_size, void* d_ws, size_t ws_size,
                              hipStream_t stream) {
    const float* x = (const float*)d_in[0];   // [128, 16384]
    const float* A = (const float*)d_in[1];   // [128, 128]
    const float* B = (const float*)d_in[2];   // [128, 8256]
    float* out = (float*)d_out;               // [128, 16384]

    ushort* wt = (ushort*)d_ws;
    ushort* pp = (ushort*)((char*)d_ws + PP_OFF);

    build_all<<<781, 256, 0, stream>>>(A, B, pp, wt, out);
    gemm_mfma<<<dim3(BATCH_ / 128, 4), 512, 0, stream>>>(x, wt, pp, out);
}

// Round 3
// 123.144 us; speedup vs baseline: 1.0494x; 1.0494x over previous
//
#include <hip/hip_runtime.h>

// out[128,16384] = [A|B](128x8384) @ [x; x2](8384x16384), fp16 MFMA.
// Round 12 = round 11 with the cvt_pkrtz type fix (returns __fp16x2 -> bitcast
// via memcpy). Theory under test (from r10's lesson: split-K x2->x4 left gemm
// time EXACTLY unchanged => a per-CU shared pipe is saturated; counters point
// at LDS: memcpy(.,.,16) from runtime offset j0a can only prove 2B alignment
// -> emitted as ~8x ds_read_u16 each, ~36 LDS instr/wave-step):
//   - b-frag j-octet reads via aligned half8 pointer cast (j0a is always a
//     multiple of 8; xt rows are 17x16B) -> true ds_read_b128, 8 LDS/step.
//   - bf16 -> fp16 everywhere: v_pk_mul_f16 multiplies packed pairs directly,
//     killing the unpack->v_pk_mul_f32->v_perm chain (~64 VALU/step -> ~20).
//     mfma_f32_16x16x32_f16 is same-rate; fp16 is MORE precise than bf16 at
//     these magnitudes (|x|<~5, |W|~0.02), so absmax should drop.
// DO NOT add __launch_bounds__ min-waves: (256,8) clamped VGPR -> spills (r6).
// K permutation: identity k'<128 (steps 0-1) | NICE [128,7936) (steps 2-123,
// uniform i, aligned j-octet) | RAGGED [7936,8384) (steps 124-130, gather).

constexpr int N_     = 128;
constexpr int S_     = 8256;
constexpr int BATCH_ = 16384;
constexpr int KTOT   = 8384;         // 131*64
constexpr int NKT    = 131;
constexpr int LD     = 136;          // xt row stride (ushorts); rows 272B = 17x16B
constexpr size_t WT_BYTES = (size_t)KTOT * 128 * 2;
constexpr size_t PP_OFF   = WT_BYTES;

typedef __attribute__((ext_vector_type(8))) _Float16 half8;
typedef __attribute__((ext_vector_type(2))) _Float16 half2t;
typedef __attribute__((ext_vector_type(4))) float f32x4;

__device__ __forceinline__ ushort f2h(float f) {     // f32 -> fp16 bits (RNE)
    _Float16 h = (_Float16)f;
    ushort b; __builtin_memcpy(&b, &h, 2); return b;
}
__device__ __forceinline__ float h2f(ushort b) {
    _Float16 h; __builtin_memcpy(&h, &b, 2); return (float)h;
}
__device__ __forceinline__ half2t duph(ushort b) {   // {h, h} packed
    uint w = ((uint)b << 16) | (uint)b;
    half2t d; __builtin_memcpy(&d, &w, 4); return d;
}
__device__ __forceinline__ half8 mul_bc(half8 w, half2t d) {  // 4x v_pk_mul_f16
    union { half8 h; half2t p[4]; } u, r;
    u.h = w;
    #pragma unroll
    for (int q = 0; q < 4; ++q) r.p[q] = u.p[q] * d;
    return r.h;
}

// ---------- closed-form permutation helpers ----------
// cumN(i) = #NICE octets for rows < i = sum_{q<i} (16 - ceil(q/8))
__device__ __forceinline__ int cumN(int i) {
    if (i <= 0) return 0;
    const int n = i - 1, t = n >> 3, r = n & 7;
    return 16 * i - (4 * t * (t + 1) + r * (t + 1));
}
// offR(i) = #ragged entries for rows < i = sum_{q<i} ((8-(q&7))&7)
__device__ __forceinline__ int offR(int i) {
    const int a = i >> 3, b = i & 7;
    const int p = b ? (8 * (b - 1) - (((b - 1) * b) >> 1)) : 0;
    return 28 * a + p;
}
__device__ __forceinline__ int triS(int i) { return i * (257 - i) / 2; }

// ---------- fused build: zero out + pp table + wt (no internal deps) ----------
// W section (blocks [0,524)): thread (ko,m) -> 8 wt elems (one b128 store).
//   wt elem e = kt*8192 + kk*4096 + wm*2048 + mt*512 + lane*8 + el holds
//   W[m = wm*64+mt*16+(lane&15)][ perm(kt*64 + kk*32 + (lane>>4)*8 + el) ]
// Z section (blocks [524,780)): zero out[128,16384].
// P section (block 780): pp[k'] = i | (j<<8)  (j=0xFF marks A column i).
__global__ __launch_bounds__(256) void build_all(
    const float* __restrict__ A, const float* __restrict__ B,
    ushort* __restrict__ pp, ushort* __restrict__ wt,
    float* __restrict__ out)
{
    const int bid = blockIdx.x, t = threadIdx.x;
    if (bid < 524) {                              // ---- W: 1048 k-octets x 128 m ----
        const int idx = bid * 256 + t;            // [0, 134144)
        const int ko  = idx >> 7;                 // k-octet
        const int m   = idx & 127;
        const int kt = ko >> 3, kk = (ko >> 2) & 1, oct = ko & 3;
        const int lane = oct * 16 + (m & 15);
        const int e0 = kt * 8192 + kk * 4096 + (m >> 6) * 2048 +
                       ((m >> 4) & 3) * 512 + lane * 8;
        float v[8];
        if (ko < 16) {                            // identity: k = ko*8+el, A[m][k]
            const int i0 = ko * 8;
            #pragma unroll
            for (int el = 0; el < 8; ++el) v[el] = A[m * 128 + i0 + el];
        } else if (ko < 992) {                    // NICE: uniform i, aligned j-octet
            const int o = ko - 16;
            int i = 0;
            #pragma unroll
            for (int st = 64; st >= 1; st >>= 1) {
                const int c = i + st;
                if (c < 128 && cumN(c) <= o) i = c;
            }
            const int jb = ((i + 7) >> 3) + (o - cumN(i));
            const int s0 = triS(i) + jb * 8 - i;  // s = tri(i) + (j - i)
            const float* bp = B + (size_t)m * S_ + s0;
            #pragma unroll
            for (int el = 0; el < 8; ++el) v[el] = bp[el];
        } else {                                  // RAGGED: per-el gather
            const int kb = ko * 8 - 7936;
            #pragma unroll
            for (int el = 0; el < 8; ++el) {
                const int kloc = kb + el;
                int i = 0;
                #pragma unroll
                for (int st = 64; st >= 1; st >>= 1) {
                    const int c = i + st;
                    if (c < 128 && offR(c) <= kloc) i = c;
                }
                v[el] = B[(size_t)m * S_ + triS(i) + (kloc - offR(i))];
            }
        }
        ushort o8[8];
        #pragma unroll
        for (int el = 0; el < 8; ++el) o8[el] = f2h(v[el]);
        __builtin_memcpy(wt + e0, o8, 16);
    } else if (bid < 780) {                       // ---- Z: zero out ----
        const int zb = bid - 524;
        f32x4* o4 = (f32x4*)out;
        #pragma unroll
        for (int c = 0; c < 4; ++c)
            o4[(size_t)zb * 2048 + c * 512 + t] = (f32x4){0.f, 0.f, 0.f, 0.f};
    } else {                                      // ---- P: pp table ----
        const int i = t;
        if (i < 128) {
            pp[i] = (ushort)(i | (0xFFu << 8));
            const int jb0 = (i + 7) >> 3;
            int kb = 128 + cumN(i) * 8;
            for (int jb = jb0; jb < 16; ++jb) {
                #pragma unroll
                for (int e = 0; e < 8; ++e)
                    pp[kb + e] = (ushort)(i | ((jb * 8 + e) << 8));
                kb += 8;
            }
            const int h = (8 - (i & 7)) & 7;
            const int rb = 7936 + offR(i);
            for (int e = 0; e < h; ++e)
                pp[rb + e] = (ushort)(i | ((i + e) << 8));
        }
    }
}

// A-frags for step kt: 8 lane-linear b128 loads (coalesced layout).
__device__ __forceinline__ void load_af(half8 af[8], const ushort* __restrict__ wt,
                                        int kt, int wm, int lane) {
    const ushort* ab = wt + ((size_t)kt << 13) + (wm << 11) + (lane << 3);
    #pragma unroll
    for (int kk = 0; kk < 2; ++kk)
        #pragma unroll
        for (int mt = 0; mt < 4; ++mt)
            af[kk * 4 + mt] = *(const half8*)(ab + (kk << 12) + (mt << 9));
}

// NICE-step: gen B-frags from compact pair word + MFMA.
// j0a/j0b are multiples of 8 and xt row bases are 16B-aligned -> the half8
// casts below are genuinely 16B-aligned => ds_read_b128 (the r11 fix).
__device__ __forceinline__ void step_nice(f32x4 acc[4][2], const half8 af[8],
                                          uint prc, const ushort* __restrict__ xr0,
                                          const ushort* __restrict__ xr1) {
    const uint i0a = prc & 0xFFu, j0a = (prc >> 8) & 0xFFu;
    const uint i0b = (prc >> 16) & 0xFFu, j0b = prc >> 24;
    // all 8 LDS reads independent -> one lgkm window
    const ushort xia0 = xr0[i0a], xia1 = xr1[i0a];
    const ushort xib0 = xr0[i0b], xib1 = xr1[i0b];
    const half8 wa0 = *(const half8*)(xr0 + j0a);
    const half8 wa1 = *(const half8*)(xr1 + j0a);
    const half8 wb0 = *(const half8*)(xr0 + j0b);
    const half8 wb1 = *(const half8*)(xr1 + j0b);

    half8 bfr[2][2];
    bfr[0][0] = mul_bc(wa0, duph(xia0));
    bfr[0][1] = mul_bc(wa1, duph(xia1));
    bfr[1][0] = mul_bc(wb0, duph(xib0));
    bfr[1][1] = mul_bc(wb1, duph(xib1));

    #pragma unroll
    for (int kk = 0; kk < 2; ++kk)
        #pragma unroll
        for (int mt = 0; mt < 4; ++mt)
            #pragma unroll
            for (int nt = 0; nt < 2; ++nt)
                acc[mt][nt] = __builtin_amdgcn_mfma_f32_16x16x32_f16(
                    af[kk * 4 + mt], bfr[kk][nt], acc[mt][nt], 0, 0, 0);
}

// ---------- phase 2: fused MFMA GEMM, 128x128 tile, split-K x4 ----------
__global__ __launch_bounds__(512) void gemm_mfma(
    const float*  __restrict__ x,
    const ushort* __restrict__ wt,
    const ushort* __restrict__ pp,
    float* __restrict__ out)
{
    __shared__ ushort xt[128 * LD];    // 34.8 KB: xt[n*LD + r] = fp16 x[r][b0+n]
    __shared__ uint   ppc[NKT * 4];    // 2.1 KB: i0a|j0a<<8|i0b<<16|j0b<<24 per (kt,quad)

    const int t    = threadIdx.x;
    const int b0   = blockIdx.x * 128;
    const int sp   = blockIdx.y;       // 0..3
    const int kt0  = sp * 33;          // 0,33,66,99
    const int kt1  = (sp == 3) ? NKT : kt0 + 33;
    const int lane = t & 63;
    const int w    = t >> 6;
    const int wm   = w >> 2, wn = w & 3;
    const int l16  = lane & 15, quad = lane >> 4;

    // ---- stage xt: coalesced global reads, RNE, b128 LDS writes ----
    {
        const int n = t & 127, g = t >> 7;
        #pragma unroll
        for (int c = 0; c < 4; ++c) {
            const int rb = g * 32 + c * 8;
            uint ow[4];
            #pragma unroll
            for (int p = 0; p < 4; ++p) {
                const ushort u0 = f2h(x[(size_t)(rb + 2 * p) * BATCH_ + b0 + n]);
                const ushort u1 = f2h(x[(size_t)(rb + 2 * p + 1) * BATCH_ + b0 + n]);
                ow[p] = (uint)u0 | ((uint)u1 << 16);
            }
            __builtin_memcpy(&xt[n * LD + rb], ow, 16);
        }
    }
    // ---- stage ppc ----
    for (int idx = t; idx < NKT * 4; idx += 512) {
        const int kt = idx >> 2, q = idx & 3;
        const uint w0 = *(const uint*)(pp + kt * 64 + q * 8);
        const uint w1 = *(const uint*)(pp + kt * 64 + 32 + q * 8);
        ppc[idx] = (w0 & 0xFFFFu) | ((w1 & 0xFFFFu) << 16);
    }
    __syncthreads();

    f32x4 acc[4][2];
    #pragma unroll
    for (int mt = 0; mt < 4; ++mt)
        #pragma unroll
        for (int nt = 0; nt < 2; ++nt)
            acc[mt][nt] = (f32x4){0.f, 0.f, 0.f, 0.f};

    const ushort* xr0 = xt + (wn * 32 + l16) * LD;
    const ushort* xr1 = xr0 + 16 * LD;

    // ================= identity steps (kt = 0,1; sp==0 only) =================
    if (sp == 0) {
        for (int kt = 0; kt < 2; ++kt) {
            half8 af[8];
            load_af(af, wt, kt, wm, lane);
            half8 bfr[2][2];
            #pragma unroll
            for (int kk = 0; kk < 2; ++kk) {
                const int off = kt * 64 + kk * 32 + quad * 8;
                bfr[kk][0] = *(const half8*)(xr0 + off);
                bfr[kk][1] = *(const half8*)(xr1 + off);
            }
            #pragma unroll
            for (int kk = 0; kk < 2; ++kk)
                #pragma unroll
                for (int mt = 0; mt < 4; ++mt)
                    #pragma unroll
                    for (int nt = 0; nt < 2; ++nt)
                        acc[mt][nt] = __builtin_amdgcn_mfma_f32_16x16x32_f16(
                            af[kk * 4 + mt], bfr[kk][nt], acc[mt][nt], 0, 0, 0);
        }
    }

    // ================= NICE steps, software-pipelined =================
    {
        const int s_ni = (kt0 > 2) ? kt0 : 2;
        const int e_ni = (kt1 < 124) ? kt1 : 124;
        int kt = s_ni;
        if (kt < e_ni) {
            half8 afA[8], afB[8];
            load_af(afA, wt, kt, wm, lane);
            uint prc = ppc[kt * 4 + quad];
            while (true) {
                {   // consume afA, prefetch afB
                    const int ktn = (kt + 1 < e_ni) ? kt + 1 : kt;
                    load_af(afB, wt, ktn, wm, lane);
                    const uint prn = ppc[ktn * 4 + quad];
                    step_nice(acc, afA, prc, xr0, xr1);
                    prc = prn; ++kt;
                }
                if (kt >= e_ni) break;
                {   // consume afB, prefetch afA
                    const int ktn = (kt + 1 < e_ni) ? kt + 1 : kt;
                    load_af(afA, wt, ktn, wm, lane);
                    const uint prn = ppc[ktn * 4 + quad];
                    step_nice(acc, afB, prc, xr0, xr1);
                    prc = prn; ++kt;
                }
                if (kt >= e_ni) break;
            }
        }
    }

    // ================= ragged steps (kt = 124..130; sp==3 only) =================
    if (sp == 3) {
        for (int kt = 124; kt < NKT; ++kt) {
            half8 af[8];
            load_af(af, wt, kt, wm, lane);
            half8 bfr[2][2];
            #pragma unroll
            for (int kk = 0; kk < 2; ++kk) {
                const int k0 = kt * 64 + kk * 32 + quad * 8;
                const uint4 pk = *(const uint4*)(pp + k0);
                const uint pr4[4] = {pk.x, pk.y, pk.z, pk.w};
                #pragma unroll
                for (int nt = 0; nt < 2; ++nt) {
                    const ushort* xr = nt ? xr1 : xr0;
                    float prods[8];
                    #pragma unroll
                    for (int e = 0; e < 8; ++e) {
                        const uint ent = (pr4[e >> 1] >> ((e & 1) * 16)) & 0xFFFFu;
                        prods[e] = h2f(xr[ent & 0xFFu]) * h2f(xr[ent >> 8]);
                    }
                    union { half8 h; uint w[4]; } bb;
                    #pragma unroll
                    for (int p = 0; p < 4; ++p) {
                        const auto pk2 = __builtin_amdgcn_cvt_pkrtz(
                            prods[2 * p], prods[2 * p + 1]);
                        __builtin_memcpy(&bb.w[p], &pk2, 4);
                    }
                    bfr[kk][nt] = bb.h;
                }
            }
            #pragma unroll
            for (int kk = 0; kk < 2; ++kk)
                #pragma unroll
                for (int mt = 0; mt < 4; ++mt)
                    #pragma unroll
                    for (int nt = 0; nt < 2; ++nt)
                        acc[mt][nt] = __builtin_amdgcn_mfma_f32_16x16x32_f16(
                            af[kk * 4 + mt], bfr[kk][nt], acc[mt][nt], 0, 0, 0);
        }
    }

    // ---- epilogue: atomic accumulate (C/D: col=lane&15, row=quad*4+reg) ----
    #pragma unroll
    for (int mt = 0; mt < 4; ++mt) {
        #pragma unroll
        for (int nt = 0; nt < 2; ++nt) {
            const int mbase = wm * 64 + mt * 16 + quad * 4;
            const size_t col = (size_t)b0 + wn * 32 + nt * 16 + l16;
            #pragma unroll
            for (int r = 0; r < 4; ++r)
                unsafeAtomicAdd(&out[(size_t)(mbase + r) * BATCH_ + col],
                                acc[mt][nt][r]);
        }
    }
}

extern "C" void kernel_launch(void* const* d_in, const int* in_sizes, int n_in,
                              void* d_out, int out_size, void* d_ws, size_t ws_size,
                              hipStream_t stream) {
    const float* x = (const float*)d_in[0];   // [128, 16384]
    const float* A = (const float*)d_in[1];   // [128, 128]
    const float* B = (const float*)d_in[2];   // [128, 8256]
    float* out = (float*)d_out;               // [128, 16384]

    ushort* wt = (ushort*)d_ws;
    ushort* pp = (ushort*)((char*)d_ws + PP_OFF);

    build_all<<<781, 256, 0, stream>>>(A, B, pp, wt, out);
    gemm_mfma<<<dim3(BATCH_ / 128, 4), 512, 0, stream>>>(x, wt, pp, out);
}